// Round 5
// baseline (962.693 us; speedup 1.0000x reference)
//
#include <hip/hip_runtime.h>
#include <math.h>

#define B_    8192
#define K_    64
#define C_    64
#define FEAT_ 172
#define TDIM_ 100
#define TOKH_ 32
#define CHH_  256
#define G_    100
#define L_    2
#define CAT_  236      // C_+FEAT_

typedef _Float16 f16x8 __attribute__((ext_vector_type(8)));
typedef _Float16 f16x4 __attribute__((ext_vector_type(4)));
typedef float    f32x4 __attribute__((ext_vector_type(4)));

// Fast exact-range cos: p is the f32 product (same rounding as the jax ref),
// reduced in f64 (exact to ~1e-10 for |p|<=2e6), then hardware v_cos.
// Replaces libm cosf's divergent Payne-Hanek slow path (~40+ inst) with ~7.
__device__ __forceinline__ float fast_cos(float p) {
    const double rev = (double)p * 0.15915494309189535;   // p / 2pi
    const double fr  = rev - __builtin_rint(rev);         // [-0.5, 0.5]
#if __has_builtin(__builtin_amdgcn_cosf)
    return __builtin_amdgcn_cosf((float)fr);              // v_cos: revolutions
#else
    return __cosf(6.283185307179586f * (float)fr);
#endif
}

// GELU via A&S 7.1.25 erf (|err|<2.5e-5), v_rcp instead of fdiv: ~13 VALU.
__device__ __forceinline__ float gelu_f(float x) {
    const float z  = x * 0.70710678118654752f;
    const float az = fabsf(z);
    const float t  = __builtin_amdgcn_rcpf(fmaf(0.47047f, az, 1.0f));
    const float poly = t * (0.3480242f + t * (-0.0958798f + t * 0.7478556f));
    const float e  = __expf(-az * az);
    float erfv = fmaf(-poly, e, 1.0f);
    erfv = copysignf(erfv, z);
    return 0.5f * x * (1.0f + erfv);
}

// ---------------------------------------------------------------------------
// Prepack weights to f16, layouts chosen so every MFMA A/B fragment is one
// contiguous 16B load.
// ---------------------------------------------------------------------------
__global__ __launch_bounds__(256)
void prepack_kernel(const float* __restrict__ proj_W,
                    const float* __restrict__ tW1, const float* __restrict__ tW2,
                    const float* __restrict__ cW1, const float* __restrict__ cW2,
                    _Float16* __restrict__ pW,
                    _Float16* __restrict__ pT1, _Float16* __restrict__ pT2,
                    _Float16* __restrict__ pC1, _Float16* __restrict__ pC2) {
    const int stride = gridDim.x * blockDim.x;
    const int t0 = blockIdx.x * blockDim.x + threadIdx.x;
    // pW[c][i] (64 x 288): = proj_W[i][c], zero-pad i>=272
    for (int i = t0; i < 64 * 288; i += stride) {
        const int c = i / 288, ii = i % 288;
        pW[i] = (ii < 272) ? (_Float16)proj_W[ii * 64 + c] : (_Float16)0.f;
    }
    // pT1[l][j][k] = tW1[l][k][j]   tW1: (2,64,32)
    for (int i = t0; i < 2 * 32 * 64; i += stride) {
        const int l = i / 2048, rem = i % 2048, j = rem / 64, k = rem % 64;
        pT1[i] = (_Float16)tW1[l * 2048 + k * 32 + j];
    }
    // pT2[l][k][j] = tW2[l][j][k]   tW2: (2,32,64)
    for (int i = t0; i < 2 * 64 * 32; i += stride) {
        const int l = i / 2048, rem = i % 2048, k = rem / 32, j = rem % 32;
        pT2[i] = (_Float16)tW2[l * 2048 + j * 64 + k];
    }
    // pC1[l][n][c] = cW1[l][c][n]   cW1: (2,64,256)
    for (int i = t0; i < 2 * 256 * 64; i += stride) {
        const int l = i / 16384, rem = i % 16384, n = rem / 64, c = rem % 64;
        pC1[i] = (_Float16)cW1[l * 16384 + c * 256 + n];
    }
    // pC2[l][c][n] = cW2[l][n][c]   cW2: (2,256,64)
    for (int i = t0; i < 2 * 64 * 256; i += stride) {
        const int l = i / 16384, rem = i % 16384, c = rem / 256, n = rem % 256;
        pC2[i] = (_Float16)cW2[l * 16384 + n * 64 + c];
    }
}

// ---------------------------------------------------------------------------
// Fused: gather+time-encode+proj (MFMA, K=288) -> 2 mixer layers -> agg.
// Structure identical to round 4 (verified). This round: fast_cos, rcp-gelu,
// and explicit register staging of all weight fragments at the top of each
// phase/q-iteration so global-load latency hides under MFMA+gelu work.
// ---------------------------------------------------------------------------
__global__ __launch_bounds__(256, 4)
void fused_kernel(const float* __restrict__ edge_table,
                  const float* __restrict__ time_w,
                  const _Float16* __restrict__ pW,
                  const float* __restrict__ proj_b,
                  const int*   __restrict__ nbr_nids,
                  const int*   __restrict__ nbr_eids,
                  const float* __restrict__ node_times,
                  const float* __restrict__ nbr_times,
                  const float* __restrict__ tok_ln_s, const float* __restrict__ tok_ln_b,
                  const float* __restrict__ tok_b1,   const float* __restrict__ tok_b2,
                  const float* __restrict__ ch_ln_s,  const float* __restrict__ ch_ln_b,
                  const float* __restrict__ ch_b1,    const float* __restrict__ ch_b2,
                  const _Float16* __restrict__ pT1, const _Float16* __restrict__ pT2,
                  const _Float16* __restrict__ pC1, const _Float16* __restrict__ pC2,
                  float* __restrict__ agg_out) {
    __shared__ __attribute__((aligned(16))) float xf[64 * 68];      // 17408 B
    __shared__ __attribute__((aligned(16))) char  Ubuf[64 * 168 * 2]; // 21504 B
    _Float16* inT = (_Float16*)Ubuf;            // proj staging [64][168]
    _Float16* xh  = (_Float16*)Ubuf;            // LN out [64][72] (9216 B)
    _Float16* hb  = (_Float16*)(Ubuf + 9216);   // token [64][40] / channel [64][72]

    const int b    = blockIdx.x;
    const int t    = threadIdx.x;
    const int lane = t & 63;
    const int w    = t >> 6;
    const int r    = lane & 15;
    const int g    = lane >> 4;
    const int row16 = 16 * w + r;

    // ================= proj phase =================
    const int kq = t >> 2;          // row 0..63
    const int q4 = t & 3;
    const size_t eid = (size_t)nbr_eids[b * K_ + kq];
    const float* erow = edge_table + eid * FEAT_;
    const int   nz = (nbr_nids[b * K_ + kq] == 0);
    const float dt = node_times[b] - nbr_times[b * K_ + kq];

    // stage chunk A: i = 0..159 (edge cols), row-local cols 0..159
    {
        _Float16* dst = inT + kq * 168;
#pragma unroll
        for (int j = 0; j < 10; ++j) {
            const float4 v = *(const float4*)(erow + 40 * q4 + 4 * j);
            f16x4 h = {(_Float16)v.x, (_Float16)v.y, (_Float16)v.z, (_Float16)v.w};
            *(f16x4*)&dst[40 * q4 + 4 * j] = h;
        }
    }
    __syncthreads();

    f32x4 pacc[4];
#pragma unroll
    for (int nt = 0; nt < 4; ++nt)
        pacc[nt] = *(const f32x4*)&proj_b[16 * nt + 4 * g];

#pragma unroll
    for (int kk = 0; kk < 5; ++kk) {
        f16x8 af[4];
#pragma unroll
        for (int nt = 0; nt < 4; ++nt)
            af[nt] = *(const f16x8*)&pW[(16 * nt + r) * 288 + 32 * kk + 8 * g];
        const f16x8 bfrag = *(const f16x8*)&inT[row16 * 168 + 32 * kk + 8 * g];
#pragma unroll
        for (int nt = 0; nt < 4; ++nt)
            pacc[nt] = __builtin_amdgcn_mfma_f32_16x16x32_f16(af[nt], bfrag, pacc[nt], 0, 0, 0);
    }
    __syncthreads();   // all reads of chunk A done before restage

    // stage chunk B: global i = 160..287 -> row-local cols 0..127
    // (local col 0..11 = edge 160..171; 12..111 = time 0..99; 112..127 = pad)
    {
        _Float16* dst = inT + kq * 168;
        if (q4 == 0) {
#pragma unroll
            for (int j = 0; j < 3; ++j) {
                const float4 v = *(const float4*)(erow + 160 + 4 * j);
                f16x4 h = {(_Float16)v.x, (_Float16)v.y, (_Float16)v.z, (_Float16)v.w};
                *(f16x4*)&dst[4 * j] = h;
            }
            for (int d = 0; d < 20; ++d)
                dst[12 + d] = nz ? (_Float16)0.f : (_Float16)fast_cos(dt * time_w[d]);
        } else if (q4 == 3) {
            for (int d = 84; d < 100; ++d)
                dst[12 + d] = nz ? (_Float16)0.f : (_Float16)fast_cos(dt * time_w[d]);
            for (int i2 = 112; i2 < 128; ++i2) dst[i2] = (_Float16)0.f;
        } else {
            for (int d = 32 * q4 - 12; d < 32 * q4 + 20; ++d)
                dst[12 + d] = nz ? (_Float16)0.f : (_Float16)fast_cos(dt * time_w[d]);
        }
    }
    __syncthreads();

#pragma unroll
    for (int kk = 0; kk < 4; ++kk) {
        f16x8 af[4];
#pragma unroll
        for (int nt = 0; nt < 4; ++nt)
            af[nt] = *(const f16x8*)&pW[(16 * nt + r) * 288 + 160 + 32 * kk + 8 * g];
        const f16x8 bfrag = *(const f16x8*)&inT[row16 * 168 + 32 * kk + 8 * g];
#pragma unroll
        for (int nt = 0; nt < 4; ++nt)
            pacc[nt] = __builtin_amdgcn_mfma_f32_16x16x32_f16(af[nt], bfrag, pacc[nt], 0, 0, 0);
    }
    // x[k][c]: lane: k = row16, c = 16nt+4g..+3
#pragma unroll
    for (int nt = 0; nt < 4; ++nt)
        *(f32x4*)&xf[row16 * 68 + 16 * nt + 4 * g] = pacc[nt];
    __syncthreads();

    // ================= mixer layers =================
    for (int l = 0; l < L_; ++l) {
        // ---- token LN (over k, per c); c-slice wave-local ----
        {
            const int c0 = row16;
            float xv[16], s = 0.f, ss = 0.f;
#pragma unroll
            for (int u = 0; u < 16; ++u) {
                const float v = xf[(16 * g + u) * 68 + c0];
                xv[u] = v; s += v; ss += v * v;
            }
            s += __shfl_xor(s, 16); ss += __shfl_xor(ss, 16);
            s += __shfl_xor(s, 32); ss += __shfl_xor(ss, 32);
            const float mean = s * 0.015625f;
            const float rstd = rsqrtf(ss * 0.015625f - mean * mean + 1e-5f);
            const float* tls = tok_ln_s + l * 64 + 16 * g;
            const float* tlb = tok_ln_b + l * 64 + 16 * g;
            f16x8 h0, h1;
#pragma unroll
            for (int u = 0; u < 8; ++u)
                h0[u] = (_Float16)((xv[u] - mean) * rstd * tls[u] + tlb[u]);
#pragma unroll
            for (int u = 0; u < 8; ++u)
                h1[u] = (_Float16)((xv[8 + u] - mean) * rstd * tls[8 + u] + tlb[8 + u]);
            *(f16x8*)&xh[c0 * 72 + 16 * g]     = h0;   // xh^T[c][k]
            *(f16x8*)&xh[c0 * 72 + 16 * g + 8] = h1;
        }
        // ---- token mixing: preload ALL weight frags, then G1 -> G2 ----
        {
            const _Float16* W1 = pT1 + l * 2048;   // [j][k]
            const _Float16* W2 = pT2 + l * 2048;   // [k][j]
            f16x8 ta[2], tb[2], wg2[4];
#pragma unroll
            for (int nt = 0; nt < 2; ++nt) {
                ta[nt] = *(const f16x8*)&W1[(16 * nt + r) * 64 + 8 * g];
                tb[nt] = *(const f16x8*)&W1[(16 * nt + r) * 64 + 32 + 8 * g];
            }
#pragma unroll
            for (int nt = 0; nt < 4; ++nt)
                wg2[nt] = *(const f16x8*)&W2[(16 * nt + r) * 32 + 8 * g];

            const f16x8 b0 = *(const f16x8*)&xh[row16 * 72 + 8 * g];
            const f16x8 b1 = *(const f16x8*)&xh[row16 * 72 + 32 + 8 * g];
            // G1: Htok[c][j] = gelu(xh^T W1 + b1)
#pragma unroll
            for (int nt = 0; nt < 2; ++nt) {
                f32x4 acc = *(const f32x4*)&tok_b1[l * 32 + 16 * nt + 4 * g];
                acc = __builtin_amdgcn_mfma_f32_16x16x32_f16(ta[nt], b0, acc, 0, 0, 0);
                acc = __builtin_amdgcn_mfma_f32_16x16x32_f16(tb[nt], b1, acc, 0, 0, 0);
                // D: j = 16nt+4g+jj, c = row16
                f16x4 hq;
#pragma unroll
                for (int jj = 0; jj < 4; ++jj) hq[jj] = (_Float16)gelu_f(acc[jj]);
                *(f16x4*)&hb[row16 * 40 + 16 * nt + 4 * g] = hq;
            }
            // G2 + residual (c-slice wave-local)
            const f16x8 a = *(const f16x8*)&hb[row16 * 40 + 8 * g];  // A: c=row16, j contig
#pragma unroll
            for (int nt = 0; nt < 4; ++nt) {
                const int kcol = 16 * nt + r;
                const float bk = tok_b2[l * 64 + kcol];
                f32x4 acc = {bk, bk, bk, bk};
                acc = __builtin_amdgcn_mfma_f32_16x16x32_f16(a, wg2[nt], acc, 0, 0, 0);
                // D: c = 16w+4g+jj, k = kcol
                float* p = &xf[kcol * 68 + 16 * w + 4 * g];
                const f32x4 old = *(const f32x4*)p;
                *(f32x4*)p = old + acc;
            }
        }
        __syncthreads();   // token residual visible to all before channel LN

        // ---- channel LN (over c, per k); k-row wave-local ----
        {
            const int k0 = row16;
            f32x4 cv[4];
            float s = 0.f, ss = 0.f;
#pragma unroll
            for (int uu = 0; uu < 4; ++uu) {
                cv[uu] = *(const f32x4*)&xf[k0 * 68 + 16 * g + 4 * uu];
#pragma unroll
                for (int e = 0; e < 4; ++e) { s += cv[uu][e]; ss += cv[uu][e] * cv[uu][e]; }
            }
            s += __shfl_xor(s, 16); ss += __shfl_xor(ss, 16);
            s += __shfl_xor(s, 32); ss += __shfl_xor(ss, 32);
            const float mean = s * 0.015625f;
            const float rstd = rsqrtf(ss * 0.015625f - mean * mean + 1e-5f);
            const float* cls = ch_ln_s + l * 64 + 16 * g;
            const float* clb = ch_ln_b + l * 64 + 16 * g;
            f16x8 h0, h1;
#pragma unroll
            for (int uu = 0; uu < 4; ++uu)
#pragma unroll
                for (int e = 0; e < 4; ++e) {
                    const float hv = (cv[uu][e] - mean) * rstd * cls[4 * uu + e] + clb[4 * uu + e];
                    if (uu < 2) h0[4 * uu + e] = (_Float16)hv;
                    else        h1[4 * (uu - 2) + e] = (_Float16)hv;
                }
            *(f16x8*)&xh[k0 * 72 + 16 * g]     = h0;   // xh[k][c]
            *(f16x8*)&xh[k0 * 72 + 16 * g + 8] = h1;
        }
        // ---- channel MLP: per q, stage all 16 weight frags, then compute ----
        {
            const f16x8 ca0 = *(const f16x8*)&xh[row16 * 72 + 8 * g];
            const f16x8 ca1 = *(const f16x8*)&xh[row16 * 72 + 32 + 8 * g];
            const _Float16* Wc1 = pC1 + l * 16384;   // [n][c]
            const _Float16* Wc2 = pC2 + l * 16384;   // [c][n]
            f32x4 cacc[4];
#pragma unroll
            for (int nt = 0; nt < 4; ++nt)
                cacc[nt] = *(const f32x4*)&ch_b2[l * 64 + 16 * nt + 4 * g];
#pragma unroll
            for (int q = 0; q < 4; ++q) {
                f16x8 w1a[4], w1b[4], w2[8];
#pragma unroll
                for (int nt = 0; nt < 4; ++nt) {
                    const int nrow = 64 * q + 16 * nt + r;
                    w1a[nt] = *(const f16x8*)&Wc1[nrow * 64 + 8 * g];
                    w1b[nt] = *(const f16x8*)&Wc1[nrow * 64 + 32 + 8 * g];
                }
#pragma unroll
                for (int ks = 0; ks < 2; ++ks)
#pragma unroll
                    for (int nt2 = 0; nt2 < 4; ++nt2)
                        w2[4 * ks + nt2] = *(const f16x8*)&Wc2[(16 * nt2 + r) * 256 + 64 * q + 32 * ks + 8 * g];
                // H = gelu(x_ln @ Wc1 + b1) for this n-quarter
                f32x4 hacc[4];
#pragma unroll
                for (int nt = 0; nt < 4; ++nt) {
                    hacc[nt] = *(const f32x4*)&ch_b1[l * 256 + 64 * q + 16 * nt + 4 * g];
                    hacc[nt] = __builtin_amdgcn_mfma_f32_16x16x32_f16(w1a[nt], ca0, hacc[nt], 0, 0, 0);
                    hacc[nt] = __builtin_amdgcn_mfma_f32_16x16x32_f16(w1b[nt], ca1, hacc[nt], 0, 0, 0);
                }
#pragma unroll
                for (int nt = 0; nt < 4; ++nt) {
                    // D: n_local = 16nt+4g+jj, k = row16
                    f16x4 hq;
#pragma unroll
                    for (int jj = 0; jj < 4; ++jj) hq[jj] = (_Float16)gelu_f(hacc[nt][jj]);
                    *(f16x4*)&hb[row16 * 72 + 16 * nt + 4 * g] = hq;
                }
                // accumulate H @ Wc2 into cacc (hb wave-local, no barrier)
#pragma unroll
                for (int ks = 0; ks < 2; ++ks) {
                    const f16x8 bh = *(const f16x8*)&hb[row16 * 72 + 32 * ks + 8 * g];
#pragma unroll
                    for (int nt2 = 0; nt2 < 4; ++nt2)
                        cacc[nt2] = __builtin_amdgcn_mfma_f32_16x16x32_f16(w2[4 * ks + nt2], bh, cacc[nt2], 0, 0, 0);
                }
            }
            // residual: lane: k = row16, c = 16nt2+4g..+3
#pragma unroll
            for (int nt2 = 0; nt2 < 4; ++nt2) {
                float* p = &xf[row16 * 68 + 16 * nt2 + 4 * g];
                const f32x4 old = *(const f32x4*)p;
                *(f32x4*)p = old + cacc[nt2];
            }
        }
        __syncthreads();   // layer complete
    }

    // ---- agg: mean over k per c ----
    {
        float ssum = 0.f;
#pragma unroll
        for (int u = 0; u < 16; ++u) ssum += xf[(16 * g + u) * 68 + row16];
        ssum += __shfl_xor(ssum, 16);
        ssum += __shfl_xor(ssum, 32);
        if (g == 0) agg_out[(size_t)b * 64 + row16] = ssum * 0.015625f;
    }
}

// ---------------------------------------------------------------------------
// Kernel 3: gap aggregation + output GEMV
// ---------------------------------------------------------------------------
__global__ __launch_bounds__(192)
void out_kernel(const float* __restrict__ node_table,
                const float* __restrict__ agg,
                const float* __restrict__ out_W,
                const float* __restrict__ out_b,
                const int*   __restrict__ node_ids,
                const int*   __restrict__ gap_ids,
                float* __restrict__ out) {
    __shared__ float inb[CAT_];
    const int b = blockIdx.x;
    const int t = threadIdx.x;

    if (t < 64) inb[t] = agg[(size_t)b * C_ + t];

    if (t < FEAT_) {
        const int* gid = gap_ids + (size_t)b * G_;
        float acc = 0.f;
        int nv = 0;
#pragma unroll 4
        for (int g = 0; g < G_; ++g) {
            const int id = gid[g];
            if (id > 0) { ++nv; acc += node_table[(size_t)id * FEAT_ + t]; }
        }
        const int nvs = (nv > 0) ? nv : 1;
        const float scale = 1.0f / (float)(G_ * nvs);
        const int nid = node_ids[b];
        inb[64 + t] = acc * scale + node_table[(size_t)nid * FEAT_ + t];
    }
    __syncthreads();

    if (t < FEAT_) {
        float o = out_b[t];
#pragma unroll 4
        for (int i = 0; i < CAT_; ++i) o += inb[i] * out_W[i * FEAT_ + t];
        out[(size_t)b * FEAT_ + t] = o;
    }
}

// ---------------------------------------------------------------------------
extern "C" void kernel_launch(void* const* d_in, const int* in_sizes, int n_in,
                              void* d_out, int out_size, void* d_ws, size_t ws_size,
                              hipStream_t stream) {
    const float* node_table = (const float*)d_in[0];
    const float* edge_table = (const float*)d_in[1];
    const float* time_w     = (const float*)d_in[2];
    const float* proj_W     = (const float*)d_in[3];
    const float* proj_b     = (const float*)d_in[4];
    const float* tok_ln_s   = (const float*)d_in[5];
    const float* tok_ln_b   = (const float*)d_in[6];
    const float* tok_W1     = (const float*)d_in[7];
    const float* tok_b1     = (const float*)d_in[8];
    const float* tok_W2     = (const float*)d_in[9];
    const float* tok_b2     = (const float*)d_in[10];
    const float* ch_ln_s    = (const float*)d_in[11];
    const float* ch_ln_b    = (const float*)d_in[12];
    const float* ch_W1      = (const float*)d_in[13];
    const float* ch_b1      = (const float*)d_in[14];
    const float* ch_W2      = (const float*)d_in[15];
    const float* ch_b2      = (const float*)d_in[16];
    const float* out_W      = (const float*)d_in[17];
    const float* out_b      = (const float*)d_in[18];
    const int*   node_ids   = (const int*)d_in[19];
    const int*   nbr_nids   = (const int*)d_in[20];
    const int*   nbr_eids   = (const int*)d_in[21];
    const int*   gap_ids    = (const int*)d_in[22];
    const float* node_times = (const float*)d_in[23];
    const float* nbr_times  = (const float*)d_in[24];

    float* agg_buf = (float*)d_ws;                       // B*C f32 = 2 MiB
    _Float16* pw   = (_Float16*)(agg_buf + (size_t)B_ * C_);
    _Float16* pW   = pw;               // 64*288   = 18432
    _Float16* pT1  = pW  + 18432;      // 2*32*64  = 4096
    _Float16* pT2  = pT1 + 4096;       // 2*64*32  = 4096
    _Float16* pC1  = pT2 + 4096;       // 2*256*64 = 32768
    _Float16* pC2  = pC1 + 32768;      // 2*64*256 = 32768
    float* outp    = (float*)d_out;

    prepack_kernel<<<64, 256, 0, stream>>>(proj_W, tok_W1, tok_W2, ch_W1, ch_W2,
                                           pW, pT1, pT2, pC1, pC2);
    fused_kernel<<<B_, 256, 0, stream>>>(edge_table, time_w, pW, proj_b,
                                         nbr_nids, nbr_eids, node_times, nbr_times,
                                         tok_ln_s, tok_ln_b, tok_b1, tok_b2,
                                         ch_ln_s, ch_ln_b, ch_b1, ch_b2,
                                         pT1, pT2, pC1, pC2,
                                         agg_buf);
    out_kernel<<<B_, 192, 0, stream>>>(node_table, agg_buf, out_W, out_b,
                                       node_ids, gap_ids, outp);
}

// Round 6
// 910.614 us; speedup vs baseline: 1.0572x; 1.0572x over previous
//
#include <hip/hip_runtime.h>
#include <math.h>

#define B_    8192
#define K_    64
#define C_    64
#define FEAT_ 172
#define TDIM_ 100
#define TOKH_ 32
#define CHH_  256
#define G_    100
#define L_    2
#define CAT_  236      // C_+FEAT_

typedef _Float16 f16x8 __attribute__((ext_vector_type(8)));
typedef _Float16 f16x4 __attribute__((ext_vector_type(4)));
typedef float    f32x4 __attribute__((ext_vector_type(4)));

// Fast exact-range cos: f32 product (same rounding as the jax ref), f64 range
// reduction (exact for |p|<=2e6), hardware v_cos (takes revolutions).
__device__ __forceinline__ float fast_cos(float p) {
    const double rev = (double)p * 0.15915494309189535;   // p / 2pi
    const double fr  = rev - __builtin_rint(rev);         // [-0.5, 0.5]
#if __has_builtin(__builtin_amdgcn_cosf)
    return __builtin_amdgcn_cosf((float)fr);
#else
    return __cosf(6.283185307179586f * (float)fr);
#endif
}

// GELU via A&S 7.1.25 erf (|err|<2.5e-5), v_rcp instead of fdiv: ~13 VALU.
__device__ __forceinline__ float gelu_f(float x) {
    const float z  = x * 0.70710678118654752f;
    const float az = fabsf(z);
    const float t  = __builtin_amdgcn_rcpf(fmaf(0.47047f, az, 1.0f));
    const float poly = t * (0.3480242f + t * (-0.0958798f + t * 0.7478556f));
    const float e  = __expf(-az * az);
    float erfv = fmaf(-poly, e, 1.0f);
    erfv = copysignf(erfv, z);
    return 0.5f * x * (1.0f + erfv);
}

// ---------------------------------------------------------------------------
// Prepack weights to f16. pW layout (64 x 288): cols 0..171 = edge weights,
// 172..175 = 0, 176..275 = time weights (d = col-176), 276..287 = 0. This
// 8-aligned split lets proj B-fragments come straight from global/registers.
// ---------------------------------------------------------------------------
__global__ __launch_bounds__(256)
void prepack_kernel(const float* __restrict__ proj_W,
                    const float* __restrict__ tW1, const float* __restrict__ tW2,
                    const float* __restrict__ cW1, const float* __restrict__ cW2,
                    _Float16* __restrict__ pW,
                    _Float16* __restrict__ pT1, _Float16* __restrict__ pT2,
                    _Float16* __restrict__ pC1, _Float16* __restrict__ pC2) {
    const int stride = gridDim.x * blockDim.x;
    const int t0 = blockIdx.x * blockDim.x + threadIdx.x;
    for (int i = t0; i < 64 * 288; i += stride) {
        const int c = i / 288, ii = i % 288;
        float v = 0.f;
        if (ii < 172) v = proj_W[ii * 64 + c];
        else if (ii >= 176 && ii < 276) v = proj_W[(ii - 4) * 64 + c];  // time row 172+(ii-176)
        pW[i] = (_Float16)v;
    }
    // pT1[l][j][k] = tW1[l][k][j]   tW1: (2,64,32)
    for (int i = t0; i < 2 * 32 * 64; i += stride) {
        const int l = i / 2048, rem = i % 2048, j = rem / 64, k = rem % 64;
        pT1[i] = (_Float16)tW1[l * 2048 + k * 32 + j];
    }
    // pT2[l][k][j] = tW2[l][j][k]   tW2: (2,32,64)
    for (int i = t0; i < 2 * 64 * 32; i += stride) {
        const int l = i / 2048, rem = i % 2048, k = rem / 32, j = rem % 32;
        pT2[i] = (_Float16)tW2[l * 2048 + j * 64 + k];
    }
    // pC1[l][n][c] = cW1[l][c][n]   cW1: (2,64,256)
    for (int i = t0; i < 2 * 256 * 64; i += stride) {
        const int l = i / 16384, rem = i % 16384, n = rem / 64, c = rem % 64;
        pC1[i] = (_Float16)cW1[l * 16384 + c * 256 + n];
    }
    // pC2[l][c][n] = cW2[l][n][c]   cW2: (2,256,64)
    for (int i = t0; i < 2 * 64 * 256; i += stride) {
        const int l = i / 16384, rem = i % 16384, c = rem / 256, n = rem % 256;
        pC2[i] = (_Float16)cW2[l * 16384 + n * 64 + c];
    }
}

// ---------------------------------------------------------------------------
// Fused: gather+time-encode+proj (MFMA K=288, NO LDS staging: per-lane direct
// global loads + in-register cos) -> 2 mixer layers -> agg.
// One b per block, 4 waves; wave w owns k-rows / c-slice [16w,16w+16).
// LDS = xf (f32 state, 17408 B) + sh (9216 B, shared xh/hb overlay; all sh
// traffic is wave-row-local so no barriers needed on it). Total 26624 B ->
// 6 blocks/CU by LDS. 2 barriers per mixer layer, 1 after proj.
// Frag maps (HW-verified r1-r4): A/B: lane l -> row/col l&15, kelem 8*(l>>4)+i;
// D: col l&15, row 4*(l>>4)+jj.
// ---------------------------------------------------------------------------
__global__ __launch_bounds__(256, 5)
void fused_kernel(const float* __restrict__ edge_table,
                  const float* __restrict__ time_w,
                  const _Float16* __restrict__ pW,
                  const float* __restrict__ proj_b,
                  const int*   __restrict__ nbr_nids,
                  const int*   __restrict__ nbr_eids,
                  const float* __restrict__ node_times,
                  const float* __restrict__ nbr_times,
                  const float* __restrict__ tok_ln_s, const float* __restrict__ tok_ln_b,
                  const float* __restrict__ tok_b1,   const float* __restrict__ tok_b2,
                  const float* __restrict__ ch_ln_s,  const float* __restrict__ ch_ln_b,
                  const float* __restrict__ ch_b1,    const float* __restrict__ ch_b2,
                  const _Float16* __restrict__ pT1, const _Float16* __restrict__ pT2,
                  const _Float16* __restrict__ pC1, const _Float16* __restrict__ pC2,
                  float* __restrict__ agg_out) {
    __shared__ __attribute__((aligned(16))) float    xf[64 * 68];   // 17408 B
    __shared__ __attribute__((aligned(16))) _Float16 sh[64 * 72];   //  9216 B

    const int b    = blockIdx.x;
    const int t    = threadIdx.x;
    const int lane = t & 63;
    const int w    = t >> 6;
    const int r    = lane & 15;
    const int g    = lane >> 4;
    const int row16 = 16 * w + r;

    // ================= proj phase (barrier-free) =================
    {
        const size_t eid  = (size_t)nbr_eids[(size_t)b * K_ + row16];
        const float* erow = edge_table + eid * FEAT_;
        const bool   nz   = (nbr_nids[(size_t)b * K_ + row16] == 0);
        const float  dt   = node_times[b] - nbr_times[(size_t)b * K_ + row16];

        f32x4 pacc[4];
#pragma unroll
        for (int nt = 0; nt < 4; ++nt)
            pacc[nt] = *(const f32x4*)&proj_b[16 * nt + 4 * g];

        const int c0b = 8 * g;
#pragma unroll
        for (int kk = 0; kk < 9; ++kk) {
            const int c0 = 32 * kk + c0b;    // this lane's K-slice [c0, c0+8)
            f16x8 bf;
            if (c0 + 8 <= FEAT_) {           // pure edge cols
                const float4 v0 = *(const float4*)(erow + c0);
                const float4 v1 = *(const float4*)(erow + c0 + 4);
                bf[0]=(_Float16)v0.x; bf[1]=(_Float16)v0.y; bf[2]=(_Float16)v0.z; bf[3]=(_Float16)v0.w;
                bf[4]=(_Float16)v1.x; bf[5]=(_Float16)v1.y; bf[6]=(_Float16)v1.z; bf[7]=(_Float16)v1.w;
            } else if (c0 < 176) {           // c0==168: edge 168..171 + 4 pad
                const float4 v0 = *(const float4*)(erow + 168);
                bf[0]=(_Float16)v0.x; bf[1]=(_Float16)v0.y; bf[2]=(_Float16)v0.z; bf[3]=(_Float16)v0.w;
                bf[4]=(_Float16)0.f; bf[5]=(_Float16)0.f; bf[6]=(_Float16)0.f; bf[7]=(_Float16)0.f;
            } else {                         // time cols: d = c0-176+i, pad >= 100
                const int d0 = c0 - 176;
#pragma unroll
                for (int i = 0; i < 8; ++i) {
                    const int d = d0 + i;
                    float tv = 0.f;
                    if (d < TDIM_) tv = fast_cos(dt * time_w[d]);
                    bf[i] = nz ? (_Float16)0.f : (_Float16)tv;
                }
            }
#pragma unroll
            for (int nt = 0; nt < 4; ++nt) {
                const f16x8 af = *(const f16x8*)&pW[(16 * nt + r) * 288 + c0];
                pacc[nt] = __builtin_amdgcn_mfma_f32_16x16x32_f16(af, bf, pacc[nt], 0, 0, 0);
            }
        }
        // x[k][c]: lane: k = row16, c = 16nt+4g..+3
#pragma unroll
        for (int nt = 0; nt < 4; ++nt)
            *(f32x4*)&xf[row16 * 68 + 16 * nt + 4 * g] = pacc[nt];
    }
    __syncthreads();

    // ================= mixer layers =================
    for (int l = 0; l < L_; ++l) {
        // ---- token LN (over k, per c); wave w owns c-slice [16w,16w+16) ----
        {
            const int c0 = row16;
            float xv[16], s = 0.f, ss = 0.f;
#pragma unroll
            for (int u = 0; u < 16; ++u) {
                const float v = xf[(16 * g + u) * 68 + c0];
                xv[u] = v; s += v; ss += v * v;
            }
            s += __shfl_xor(s, 16); ss += __shfl_xor(ss, 16);
            s += __shfl_xor(s, 32); ss += __shfl_xor(ss, 32);
            const float mean = s * 0.015625f;
            const float rstd = rsqrtf(ss * 0.015625f - mean * mean + 1e-5f);
            const float* tls = tok_ln_s + l * 64 + 16 * g;
            const float* tlb = tok_ln_b + l * 64 + 16 * g;
            f16x8 h0, h1;
#pragma unroll
            for (int u = 0; u < 8; ++u)
                h0[u] = (_Float16)((xv[u] - mean) * rstd * tls[u] + tlb[u]);
#pragma unroll
            for (int u = 0; u < 8; ++u)
                h1[u] = (_Float16)((xv[8 + u] - mean) * rstd * tls[8 + u] + tlb[8 + u]);
            *(f16x8*)&sh[c0 * 72 + 16 * g]     = h0;   // xh^T[c][k]
            *(f16x8*)&sh[c0 * 72 + 16 * g + 8] = h1;
        }
        // ---- token G1: H[c][j] = gelu(xh^T W1 + b1); then G2 + residual ----
        {
            const _Float16* W1 = pT1 + l * 2048;   // [j][k]
            const _Float16* W2 = pT2 + l * 2048;   // [k][j]
            const f16x8 b0 = *(const f16x8*)&sh[row16 * 72 + 8 * g];
            const f16x8 b1 = *(const f16x8*)&sh[row16 * 72 + 32 + 8 * g];
#pragma unroll
            for (int nt = 0; nt < 2; ++nt) {
                f32x4 acc = *(const f32x4*)&tok_b1[l * 32 + 16 * nt + 4 * g];
                const f16x8 a0 = *(const f16x8*)&W1[(16 * nt + r) * 64 + 8 * g];
                const f16x8 a1 = *(const f16x8*)&W1[(16 * nt + r) * 64 + 32 + 8 * g];
                acc = __builtin_amdgcn_mfma_f32_16x16x32_f16(a0, b0, acc, 0, 0, 0);
                acc = __builtin_amdgcn_mfma_f32_16x16x32_f16(a1, b1, acc, 0, 0, 0);
                // D: j = 16nt+4g+jj, c = row16 -> hb cols 0..31 (wave-row-local)
                f16x4 hq;
#pragma unroll
                for (int jj = 0; jj < 4; ++jj) hq[jj] = (_Float16)gelu_f(acc[jj]);
                *(f16x4*)&sh[row16 * 72 + 16 * nt + 4 * g] = hq;
            }
            const f16x8 a = *(const f16x8*)&sh[row16 * 72 + 8 * g];  // H: c=row16, j contig
#pragma unroll
            for (int nt = 0; nt < 4; ++nt) {
                const int kcol = 16 * nt + r;
                const float bk = tok_b2[l * 64 + kcol];
                f32x4 acc = {bk, bk, bk, bk};
                const f16x8 bf = *(const f16x8*)&W2[kcol * 32 + 8 * g];
                acc = __builtin_amdgcn_mfma_f32_16x16x32_f16(a, bf, acc, 0, 0, 0);
                // D: c = 16w+4g+jj, k = kcol  (RMW only this wave's c-slice)
                float* p = &xf[kcol * 68 + 16 * w + 4 * g];
                const f32x4 old = *(const f32x4*)p;
                *(f32x4*)p = old + acc;
            }
        }
        __syncthreads();   // token residual visible before channel LN

        // ---- channel LN (over c, per k); wave w owns k-rows [16w,16w+16) ----
        {
            const int k0 = row16;
            f32x4 cv[4];
            float s = 0.f, ss = 0.f;
#pragma unroll
            for (int uu = 0; uu < 4; ++uu) {
                cv[uu] = *(const f32x4*)&xf[k0 * 68 + 16 * g + 4 * uu];
#pragma unroll
                for (int e = 0; e < 4; ++e) { s += cv[uu][e]; ss += cv[uu][e] * cv[uu][e]; }
            }
            s += __shfl_xor(s, 16); ss += __shfl_xor(ss, 16);
            s += __shfl_xor(s, 32); ss += __shfl_xor(ss, 32);
            const float mean = s * 0.015625f;
            const float rstd = rsqrtf(ss * 0.015625f - mean * mean + 1e-5f);
            const float* cls = ch_ln_s + l * 64 + 16 * g;
            const float* clb = ch_ln_b + l * 64 + 16 * g;
            f16x8 h0, h1;
#pragma unroll
            for (int uu = 0; uu < 4; ++uu)
#pragma unroll
                for (int e = 0; e < 4; ++e) {
                    const float hv = (cv[uu][e] - mean) * rstd * cls[4 * uu + e] + clb[4 * uu + e];
                    if (uu < 2) h0[4 * uu + e] = (_Float16)hv;
                    else        h1[4 * (uu - 2) + e] = (_Float16)hv;
                }
            *(f16x8*)&sh[k0 * 72 + 16 * g]     = h0;   // xh[k][c]
            *(f16x8*)&sh[k0 * 72 + 16 * g + 8] = h1;
        }
        // ---- channel MLP (4 n-quarters; H overlay in sh, wave-row-local) ----
        {
            const f16x8 ca0 = *(const f16x8*)&sh[row16 * 72 + 8 * g];
            const f16x8 ca1 = *(const f16x8*)&sh[row16 * 72 + 32 + 8 * g];
            const _Float16* Wc1 = pC1 + l * 16384;   // [n][c]
            const _Float16* Wc2 = pC2 + l * 16384;   // [c][n]
            f32x4 cacc[4];
#pragma unroll
            for (int nt = 0; nt < 4; ++nt)
                cacc[nt] = *(const f32x4*)&ch_b2[l * 64 + 16 * nt + 4 * g];
            for (int q = 0; q < 4; ++q) {
#pragma unroll
                for (int nt = 0; nt < 4; ++nt) {
                    const int nrow = 64 * q + 16 * nt + r;
                    f32x4 acc = *(const f32x4*)&ch_b1[l * 256 + 64 * q + 16 * nt + 4 * g];
                    const f16x8 a0 = *(const f16x8*)&Wc1[nrow * 64 + 8 * g];
                    const f16x8 a1 = *(const f16x8*)&Wc1[nrow * 64 + 32 + 8 * g];
                    acc = __builtin_amdgcn_mfma_f32_16x16x32_f16(a0, ca0, acc, 0, 0, 0);
                    acc = __builtin_amdgcn_mfma_f32_16x16x32_f16(a1, ca1, acc, 0, 0, 0);
                    // D: n_local = 16nt+4g+jj, k = row16 -> H cols 0..63
                    f16x4 hq;
#pragma unroll
                    for (int jj = 0; jj < 4; ++jj) hq[jj] = (_Float16)gelu_f(acc[jj]);
                    *(f16x4*)&sh[row16 * 72 + 16 * nt + 4 * g] = hq;
                }
#pragma unroll
                for (int ks = 0; ks < 2; ++ks) {
                    const f16x8 bh = *(const f16x8*)&sh[row16 * 72 + 32 * ks + 8 * g];
#pragma unroll
                    for (int nt2 = 0; nt2 < 4; ++nt2) {
                        const f16x8 a2 = *(const f16x8*)&Wc2[(16 * nt2 + r) * 256 + 64 * q + 32 * ks + 8 * g];
                        cacc[nt2] = __builtin_amdgcn_mfma_f32_16x16x32_f16(a2, bh, cacc[nt2], 0, 0, 0);
                    }
                }
            }
            // residual: lane: k = row16, c = 16nt2+4g..+3
#pragma unroll
            for (int nt2 = 0; nt2 < 4; ++nt2) {
                float* p = &xf[row16 * 68 + 16 * nt2 + 4 * g];
                const f32x4 old = *(const f32x4*)p;
                *(f32x4*)p = old + cacc[nt2];
            }
        }
        __syncthreads();   // layer complete
    }

    // ---- agg: mean over k per c ----
    {
        float ssum = 0.f;
#pragma unroll
        for (int u = 0; u < 16; ++u) ssum += xf[(16 * g + u) * 68 + row16];
        ssum += __shfl_xor(ssum, 16);
        ssum += __shfl_xor(ssum, 32);
        if (g == 0) agg_out[(size_t)b * 64 + row16] = ssum * 0.015625f;
    }
}

// ---------------------------------------------------------------------------
// Kernel 3: gap aggregation + output GEMV
// ---------------------------------------------------------------------------
__global__ __launch_bounds__(192)
void out_kernel(const float* __restrict__ node_table,
                const float* __restrict__ agg,
                const float* __restrict__ out_W,
                const float* __restrict__ out_b,
                const int*   __restrict__ node_ids,
                const int*   __restrict__ gap_ids,
                float* __restrict__ out) {
    __shared__ float inb[CAT_];
    const int b = blockIdx.x;
    const int t = threadIdx.x;

    if (t < 64) inb[t] = agg[(size_t)b * C_ + t];

    if (t < FEAT_) {
        const int* gid = gap_ids + (size_t)b * G_;
        float acc = 0.f;
        int nv = 0;
#pragma unroll 4
        for (int g = 0; g < G_; ++g) {
            const int id = gid[g];
            if (id > 0) { ++nv; acc += node_table[(size_t)id * FEAT_ + t]; }
        }
        const int nvs = (nv > 0) ? nv : 1;
        const float scale = 1.0f / (float)(G_ * nvs);
        const int nid = node_ids[b];
        inb[64 + t] = acc * scale + node_table[(size_t)nid * FEAT_ + t];
    }
    __syncthreads();

    if (t < FEAT_) {
        float o = out_b[t];
#pragma unroll 4
        for (int i = 0; i < CAT_; ++i) o += inb[i] * out_W[i * FEAT_ + t];
        out[(size_t)b * FEAT_ + t] = o;
    }
}

// ---------------------------------------------------------------------------
extern "C" void kernel_launch(void* const* d_in, const int* in_sizes, int n_in,
                              void* d_out, int out_size, void* d_ws, size_t ws_size,
                              hipStream_t stream) {
    const float* node_table = (const float*)d_in[0];
    const float* edge_table = (const float*)d_in[1];
    const float* time_w     = (const float*)d_in[2];
    const float* proj_W     = (const float*)d_in[3];
    const float* proj_b     = (const float*)d_in[4];
    const float* tok_ln_s   = (const float*)d_in[5];
    const float* tok_ln_b   = (const float*)d_in[6];
    const float* tok_W1     = (const float*)d_in[7];
    const float* tok_b1     = (const float*)d_in[8];
    const float* tok_W2     = (const float*)d_in[9];
    const float* tok_b2     = (const float*)d_in[10];
    const float* ch_ln_s    = (const float*)d_in[11];
    const float* ch_ln_b    = (const float*)d_in[12];
    const float* ch_W1      = (const float*)d_in[13];
    const float* ch_b1      = (const float*)d_in[14];
    const float* ch_W2      = (const float*)d_in[15];
    const float* ch_b2      = (const float*)d_in[16];
    const float* out_W      = (const float*)d_in[17];
    const float* out_b      = (const float*)d_in[18];
    const int*   node_ids   = (const int*)d_in[19];
    const int*   nbr_nids   = (const int*)d_in[20];
    const int*   nbr_eids   = (const int*)d_in[21];
    const int*   gap_ids    = (const int*)d_in[22];
    const float* node_times = (const float*)d_in[23];
    const float* nbr_times  = (const float*)d_in[24];

    float* agg_buf = (float*)d_ws;                       // B*C f32 = 2 MiB
    _Float16* pw   = (_Float16*)(agg_buf + (size_t)B_ * C_);
    _Float16* pW   = pw;               // 64*288   = 18432
    _Float16* pT1  = pW  + 18432;      // 2*32*64  = 4096
    _Float16* pT2  = pT1 + 4096;       // 2*64*32  = 4096
    _Float16* pC1  = pT2 + 4096;       // 2*256*64 = 32768
    _Float16* pC2  = pC1 + 32768;      // 2*64*256 = 32768
    float* outp    = (float*)d_out;

    prepack_kernel<<<64, 256, 0, stream>>>(proj_W, tok_W1, tok_W2, ch_W1, ch_W2,
                                           pW, pT1, pT2, pC1, pC2);
    fused_kernel<<<B_, 256, 0, stream>>>(edge_table, time_w, pW, proj_b,
                                         nbr_nids, nbr_eids, node_times, nbr_times,
                                         tok_ln_s, tok_ln_b, tok_b1, tok_b2,
                                         ch_ln_s, ch_ln_b, ch_b1, ch_b2,
                                         pT1, pT2, pC1, pC2,
                                         agg_buf);
    out_kernel<<<B_, 192, 0, stream>>>(node_table, agg_buf, out_W, out_b,
                                       node_ids, gap_ids, outp);
}

// Round 7
// 776.227 us; speedup vs baseline: 1.2402x; 1.1731x over previous
//
#include <hip/hip_runtime.h>
#include <math.h>

#define B_    8192
#define K_    64
#define C_    64
#define FEAT_ 172
#define TDIM_ 100
#define TOKH_ 32
#define CHH_  256
#define G_    100
#define L_    2
#define CAT_  236      // C_+FEAT_

typedef _Float16 f16x8 __attribute__((ext_vector_type(8)));
typedef _Float16 f16x4 __attribute__((ext_vector_type(4)));
typedef float    f32x4 __attribute__((ext_vector_type(4)));

// Fast exact-range cos: f32 product (same rounding as the jax ref), f64 range
// reduction (exact for |p|<=2e6), hardware v_cos (takes revolutions).
__device__ __forceinline__ float fast_cos(float p) {
    const double rev = (double)p * 0.15915494309189535;   // p / 2pi
    const double fr  = rev - __builtin_rint(rev);         // [-0.5, 0.5]
#if __has_builtin(__builtin_amdgcn_cosf)
    return __builtin_amdgcn_cosf((float)fr);
#else
    return __cosf(6.283185307179586f * (float)fr);
#endif
}

// GELU via A&S 7.1.25 erf (|err|<2.5e-5), v_rcp instead of fdiv: ~13 VALU.
__device__ __forceinline__ float gelu_f(float x) {
    const float z  = x * 0.70710678118654752f;
    const float az = fabsf(z);
    const float t  = __builtin_amdgcn_rcpf(fmaf(0.47047f, az, 1.0f));
    const float poly = t * (0.3480242f + t * (-0.0958798f + t * 0.7478556f));
    const float e  = __expf(-az * az);
    float erfv = fmaf(-poly, e, 1.0f);
    erfv = copysignf(erfv, z);
    return 0.5f * x * (1.0f + erfv);
}

// ---------------------------------------------------------------------------
// Prepack weights to f16. pW layout (64 x 288): cols 0..171 = edge weights,
// 172..175 = 0, 176..275 = time weights (d = col-176), 276..287 = 0.
// ---------------------------------------------------------------------------
__global__ __launch_bounds__(256)
void prepack_kernel(const float* __restrict__ proj_W,
                    const float* __restrict__ tW1, const float* __restrict__ tW2,
                    const float* __restrict__ cW1, const float* __restrict__ cW2,
                    _Float16* __restrict__ pW,
                    _Float16* __restrict__ pT1, _Float16* __restrict__ pT2,
                    _Float16* __restrict__ pC1, _Float16* __restrict__ pC2) {
    const int stride = gridDim.x * blockDim.x;
    const int t0 = blockIdx.x * blockDim.x + threadIdx.x;
    for (int i = t0; i < 64 * 288; i += stride) {
        const int c = i / 288, ii = i % 288;
        float v = 0.f;
        if (ii < 172) v = proj_W[ii * 64 + c];
        else if (ii >= 176 && ii < 276) v = proj_W[(ii - 4) * 64 + c];
        pW[i] = (_Float16)v;
    }
    // pT1[l][j][k] = tW1[l][k][j]   tW1: (2,64,32)
    for (int i = t0; i < 2 * 32 * 64; i += stride) {
        const int l = i / 2048, rem = i % 2048, j = rem / 64, k = rem % 64;
        pT1[i] = (_Float16)tW1[l * 2048 + k * 32 + j];
    }
    // pT2[l][k][j] = tW2[l][j][k]   tW2: (2,32,64)
    for (int i = t0; i < 2 * 64 * 32; i += stride) {
        const int l = i / 2048, rem = i % 2048, k = rem / 32, j = rem % 32;
        pT2[i] = (_Float16)tW2[l * 2048 + j * 64 + k];
    }
    // pC1[l][n][c] = cW1[l][c][n]   cW1: (2,64,256)
    for (int i = t0; i < 2 * 256 * 64; i += stride) {
        const int l = i / 16384, rem = i % 16384, n = rem / 64, c = rem % 64;
        pC1[i] = (_Float16)cW1[l * 16384 + c * 256 + n];
    }
    // pC2[l][c][n] = cW2[l][n][c]   cW2: (2,256,64)
    for (int i = t0; i < 2 * 64 * 256; i += stride) {
        const int l = i / 16384, rem = i % 16384, c = rem / 256, n = rem % 256;
        pC2[i] = (_Float16)cW2[l * 16384 + n * 64 + c];
    }
}

// ---------------------------------------------------------------------------
// Fused kernel, TWO batch elements per block (b0 = 2*bid, b1 = 2*bid+1).
// Every weight fragment is loaded once per wave and feeds 2 MFMAs -> weight
// traffic halves (6 GB -> 3 GB/dispatch) and each wave carries two
// independent dependency chains (latency self-hiding). Same verified frag
// maps / wave-ownership as rounds 4-6: wave w owns k-rows and c-slice
// [16w,16w+16) of both b. LDS 53.2 KB -> 3 blocks/CU.
// ---------------------------------------------------------------------------
__global__ __launch_bounds__(256, 4)
void fused_kernel(const float* __restrict__ edge_table,
                  const float* __restrict__ time_w,
                  const _Float16* __restrict__ pW,
                  const float* __restrict__ proj_b,
                  const int*   __restrict__ nbr_nids,
                  const int*   __restrict__ nbr_eids,
                  const float* __restrict__ node_times,
                  const float* __restrict__ nbr_times,
                  const float* __restrict__ tok_ln_s, const float* __restrict__ tok_ln_b,
                  const float* __restrict__ tok_b1,   const float* __restrict__ tok_b2,
                  const float* __restrict__ ch_ln_s,  const float* __restrict__ ch_ln_b,
                  const float* __restrict__ ch_b1,    const float* __restrict__ ch_b2,
                  const _Float16* __restrict__ pT1, const _Float16* __restrict__ pT2,
                  const _Float16* __restrict__ pC1, const _Float16* __restrict__ pC2,
                  float* __restrict__ agg_out) {
    __shared__ __attribute__((aligned(16))) float    xf[2][64 * 68];   // 34816 B
    __shared__ __attribute__((aligned(16))) _Float16 sh[2][64 * 72];   // 18432 B

    const int bid  = blockIdx.x;
    const int t    = threadIdx.x;
    const int lane = t & 63;
    const int w    = t >> 6;
    const int r    = lane & 15;
    const int g    = lane >> 4;
    const int row16 = 16 * w + r;

    // ================= proj phase (both b, shared pW frags) =================
    {
        const float* erow[2];
        bool  nz[2];
        float dt[2];
#pragma unroll
        for (int bb = 0; bb < 2; ++bb) {
            const size_t bgl = (size_t)(2 * bid + bb) * K_ + row16;
            erow[bb] = edge_table + (size_t)nbr_eids[bgl] * FEAT_;
            nz[bb]   = (nbr_nids[bgl] == 0);
            dt[bb]   = node_times[2 * bid + bb] - nbr_times[bgl];
        }

        f32x4 pacc[2][4];
#pragma unroll
        for (int nt = 0; nt < 4; ++nt) {
            const f32x4 pb = *(const f32x4*)&proj_b[16 * nt + 4 * g];
            pacc[0][nt] = pb; pacc[1][nt] = pb;
        }

        const int c0b = 8 * g;
#pragma unroll
        for (int kk = 0; kk < 9; ++kk) {
            const int c0 = 32 * kk + c0b;
            f16x8 af[4];
#pragma unroll
            for (int nt = 0; nt < 4; ++nt)
                af[nt] = *(const f16x8*)&pW[(16 * nt + r) * 288 + c0];
            f16x8 bf[2];
#pragma unroll
            for (int bb = 0; bb < 2; ++bb) {
                if (c0 + 8 <= FEAT_) {
                    const float4 v0 = *(const float4*)(erow[bb] + c0);
                    const float4 v1 = *(const float4*)(erow[bb] + c0 + 4);
                    bf[bb][0]=(_Float16)v0.x; bf[bb][1]=(_Float16)v0.y;
                    bf[bb][2]=(_Float16)v0.z; bf[bb][3]=(_Float16)v0.w;
                    bf[bb][4]=(_Float16)v1.x; bf[bb][5]=(_Float16)v1.y;
                    bf[bb][6]=(_Float16)v1.z; bf[bb][7]=(_Float16)v1.w;
                } else if (c0 < 176) {       // c0==168: edge 168..171 + pad
                    const float4 v0 = *(const float4*)(erow[bb] + 168);
                    bf[bb][0]=(_Float16)v0.x; bf[bb][1]=(_Float16)v0.y;
                    bf[bb][2]=(_Float16)v0.z; bf[bb][3]=(_Float16)v0.w;
                    bf[bb][4]=(_Float16)0.f; bf[bb][5]=(_Float16)0.f;
                    bf[bb][6]=(_Float16)0.f; bf[bb][7]=(_Float16)0.f;
                } else {                     // time cols
                    const int d0 = c0 - 176;
#pragma unroll
                    for (int i = 0; i < 8; ++i) {
                        const int d = d0 + i;
                        float tv = 0.f;
                        if (d < TDIM_) tv = fast_cos(dt[bb] * time_w[d]);
                        bf[bb][i] = nz[bb] ? (_Float16)0.f : (_Float16)tv;
                    }
                }
            }
#pragma unroll
            for (int nt = 0; nt < 4; ++nt) {
                pacc[0][nt] = __builtin_amdgcn_mfma_f32_16x16x32_f16(af[nt], bf[0], pacc[0][nt], 0, 0, 0);
                pacc[1][nt] = __builtin_amdgcn_mfma_f32_16x16x32_f16(af[nt], bf[1], pacc[1][nt], 0, 0, 0);
            }
        }
#pragma unroll
        for (int bb = 0; bb < 2; ++bb)
#pragma unroll
            for (int nt = 0; nt < 4; ++nt)
                *(f32x4*)&xf[bb][row16 * 68 + 16 * nt + 4 * g] = pacc[bb][nt];
    }
    __syncthreads();

    // ================= mixer layers =================
    for (int l = 0; l < L_; ++l) {
        // ---- token LN (over k, per c), both b ----
#pragma unroll
        for (int bb = 0; bb < 2; ++bb) {
            const int c0 = row16;
            float xv[16], s = 0.f, ss = 0.f;
#pragma unroll
            for (int u = 0; u < 16; ++u) {
                const float v = xf[bb][(16 * g + u) * 68 + c0];
                xv[u] = v; s += v; ss += v * v;
            }
            s += __shfl_xor(s, 16); ss += __shfl_xor(ss, 16);
            s += __shfl_xor(s, 32); ss += __shfl_xor(ss, 32);
            const float mean = s * 0.015625f;
            const float rstd = rsqrtf(ss * 0.015625f - mean * mean + 1e-5f);
            const float* tls = tok_ln_s + l * 64 + 16 * g;
            const float* tlb = tok_ln_b + l * 64 + 16 * g;
            f16x8 h0, h1;
#pragma unroll
            for (int u = 0; u < 8; ++u)
                h0[u] = (_Float16)((xv[u] - mean) * rstd * tls[u] + tlb[u]);
#pragma unroll
            for (int u = 0; u < 8; ++u)
                h1[u] = (_Float16)((xv[8 + u] - mean) * rstd * tls[8 + u] + tlb[8 + u]);
            *(f16x8*)&sh[bb][c0 * 72 + 16 * g]     = h0;   // xh^T[c][k]
            *(f16x8*)&sh[bb][c0 * 72 + 16 * g + 8] = h1;
        }
        // ---- token G1 + G2 + residual (weight frags shared across b) ----
        {
            const _Float16* W1 = pT1 + l * 2048;   // [j][k]
            const _Float16* W2 = pT2 + l * 2048;   // [k][j]
            // read xh frags for both b BEFORE hb overwrites (same rows)
            f16x8 tb0[2], tb1[2];
#pragma unroll
            for (int bb = 0; bb < 2; ++bb) {
                tb0[bb] = *(const f16x8*)&sh[bb][row16 * 72 + 8 * g];
                tb1[bb] = *(const f16x8*)&sh[bb][row16 * 72 + 32 + 8 * g];
            }
#pragma unroll
            for (int nt = 0; nt < 2; ++nt) {
                const f16x8 a0 = *(const f16x8*)&W1[(16 * nt + r) * 64 + 8 * g];
                const f16x8 a1 = *(const f16x8*)&W1[(16 * nt + r) * 64 + 32 + 8 * g];
                const f32x4 bias = *(const f32x4*)&tok_b1[l * 32 + 16 * nt + 4 * g];
#pragma unroll
                for (int bb = 0; bb < 2; ++bb) {
                    f32x4 acc = bias;
                    acc = __builtin_amdgcn_mfma_f32_16x16x32_f16(a0, tb0[bb], acc, 0, 0, 0);
                    acc = __builtin_amdgcn_mfma_f32_16x16x32_f16(a1, tb1[bb], acc, 0, 0, 0);
                    f16x4 hq;
#pragma unroll
                    for (int jj = 0; jj < 4; ++jj) hq[jj] = (_Float16)gelu_f(acc[jj]);
                    *(f16x4*)&sh[bb][row16 * 72 + 16 * nt + 4 * g] = hq;   // hb cols 0..31
                }
            }
            f16x8 a[2];
#pragma unroll
            for (int bb = 0; bb < 2; ++bb)
                a[bb] = *(const f16x8*)&sh[bb][row16 * 72 + 8 * g];   // H: c=row16
#pragma unroll
            for (int nt = 0; nt < 4; ++nt) {
                const int kcol = 16 * nt + r;
                const float bk = tok_b2[l * 64 + kcol];
                const f16x8 bf = *(const f16x8*)&W2[kcol * 32 + 8 * g];
#pragma unroll
                for (int bb = 0; bb < 2; ++bb) {
                    f32x4 acc = {bk, bk, bk, bk};
                    acc = __builtin_amdgcn_mfma_f32_16x16x32_f16(a[bb], bf, acc, 0, 0, 0);
                    float* p = &xf[bb][kcol * 68 + 16 * w + 4 * g];
                    const f32x4 old = *(const f32x4*)p;
                    *(f32x4*)p = old + acc;   // wave's own c-slice only
                }
            }
        }
        __syncthreads();   // token residual visible before channel LN

        // ---- channel LN (over c, per k), both b ----
#pragma unroll
        for (int bb = 0; bb < 2; ++bb) {
            const int k0 = row16;
            f32x4 cv[4];
            float s = 0.f, ss = 0.f;
#pragma unroll
            for (int uu = 0; uu < 4; ++uu) {
                cv[uu] = *(const f32x4*)&xf[bb][k0 * 68 + 16 * g + 4 * uu];
#pragma unroll
                for (int e = 0; e < 4; ++e) { s += cv[uu][e]; ss += cv[uu][e] * cv[uu][e]; }
            }
            s += __shfl_xor(s, 16); ss += __shfl_xor(ss, 16);
            s += __shfl_xor(s, 32); ss += __shfl_xor(ss, 32);
            const float mean = s * 0.015625f;
            const float rstd = rsqrtf(ss * 0.015625f - mean * mean + 1e-5f);
            const float* cls = ch_ln_s + l * 64 + 16 * g;
            const float* clb = ch_ln_b + l * 64 + 16 * g;
            f16x8 h0, h1;
#pragma unroll
            for (int uu = 0; uu < 4; ++uu)
#pragma unroll
                for (int e = 0; e < 4; ++e) {
                    const float hv = (cv[uu][e] - mean) * rstd * cls[4 * uu + e] + clb[4 * uu + e];
                    if (uu < 2) h0[4 * uu + e] = (_Float16)hv;
                    else        h1[4 * (uu - 2) + e] = (_Float16)hv;
                }
            *(f16x8*)&sh[bb][k0 * 72 + 16 * g]     = h0;   // xh[k][c]
            *(f16x8*)&sh[bb][k0 * 72 + 16 * g + 8] = h1;
        }
        // ---- channel MLP (shared Wc1/Wc2 frags, 2 MFMA per frag) ----
        {
            f16x8 ca0[2], ca1[2];
#pragma unroll
            for (int bb = 0; bb < 2; ++bb) {
                ca0[bb] = *(const f16x8*)&sh[bb][row16 * 72 + 8 * g];
                ca1[bb] = *(const f16x8*)&sh[bb][row16 * 72 + 32 + 8 * g];
            }
            const _Float16* Wc1 = pC1 + l * 16384;   // [n][c]
            const _Float16* Wc2 = pC2 + l * 16384;   // [c][n]
            f32x4 cacc[2][4];
#pragma unroll
            for (int nt = 0; nt < 4; ++nt) {
                const f32x4 cb = *(const f32x4*)&ch_b2[l * 64 + 16 * nt + 4 * g];
                cacc[0][nt] = cb; cacc[1][nt] = cb;
            }
            for (int q = 0; q < 4; ++q) {
#pragma unroll
                for (int nt = 0; nt < 4; ++nt) {
                    const int nrow = 64 * q + 16 * nt + r;
                    const f16x8 a0 = *(const f16x8*)&Wc1[nrow * 64 + 8 * g];
                    const f16x8 a1 = *(const f16x8*)&Wc1[nrow * 64 + 32 + 8 * g];
                    const f32x4 hb1 = *(const f32x4*)&ch_b1[l * 256 + 64 * q + 16 * nt + 4 * g];
#pragma unroll
                    for (int bb = 0; bb < 2; ++bb) {
                        f32x4 acc = hb1;
                        acc = __builtin_amdgcn_mfma_f32_16x16x32_f16(a0, ca0[bb], acc, 0, 0, 0);
                        acc = __builtin_amdgcn_mfma_f32_16x16x32_f16(a1, ca1[bb], acc, 0, 0, 0);
                        f16x4 hq;
#pragma unroll
                        for (int jj = 0; jj < 4; ++jj) hq[jj] = (_Float16)gelu_f(acc[jj]);
                        *(f16x4*)&sh[bb][row16 * 72 + 16 * nt + 4 * g] = hq;   // H cols 0..63
                    }
                }
#pragma unroll
                for (int ks = 0; ks < 2; ++ks) {
                    f16x8 bh[2];
#pragma unroll
                    for (int bb = 0; bb < 2; ++bb)
                        bh[bb] = *(const f16x8*)&sh[bb][row16 * 72 + 32 * ks + 8 * g];
#pragma unroll
                    for (int nt2 = 0; nt2 < 4; ++nt2) {
                        const f16x8 a2 = *(const f16x8*)&Wc2[(16 * nt2 + r) * 256 + 64 * q + 32 * ks + 8 * g];
                        cacc[0][nt2] = __builtin_amdgcn_mfma_f32_16x16x32_f16(a2, bh[0], cacc[0][nt2], 0, 0, 0);
                        cacc[1][nt2] = __builtin_amdgcn_mfma_f32_16x16x32_f16(a2, bh[1], cacc[1][nt2], 0, 0, 0);
                    }
                }
            }
#pragma unroll
            for (int bb = 0; bb < 2; ++bb)
#pragma unroll
                for (int nt2 = 0; nt2 < 4; ++nt2) {
                    float* p = &xf[bb][row16 * 68 + 16 * nt2 + 4 * g];
                    const f32x4 old = *(const f32x4*)p;
                    *(f32x4*)p = old + cacc[bb][nt2];
                }
        }
        __syncthreads();   // layer complete
    }

    // ---- agg: mean over k per c, both b ----
#pragma unroll
    for (int bb = 0; bb < 2; ++bb) {
        float ssum = 0.f;
#pragma unroll
        for (int u = 0; u < 16; ++u) ssum += xf[bb][(16 * g + u) * 68 + row16];
        ssum += __shfl_xor(ssum, 16);
        ssum += __shfl_xor(ssum, 32);
        if (g == 0) agg_out[(size_t)(2 * bid + bb) * 64 + row16] = ssum * 0.015625f;
    }
}

// ---------------------------------------------------------------------------
// Kernel 3: gap aggregation + output GEMV. 384 threads = 2 groups of 192;
// gap loop and GEMV are split across groups to halve the latency chains.
// ---------------------------------------------------------------------------
__global__ __launch_bounds__(384)
void out_kernel(const float* __restrict__ node_table,
                const float* __restrict__ agg,
                const float* __restrict__ out_W,
                const float* __restrict__ out_b,
                const int*   __restrict__ node_ids,
                const int*   __restrict__ gap_ids,
                float* __restrict__ out) {
    __shared__ float inb[CAT_];
    __shared__ float part[FEAT_];
    __shared__ int   nv2;
    const int b   = blockIdx.x;
    const int t   = threadIdx.x;
    const int grp = t / 192;
    const int tl  = t - 192 * grp;

    if (grp == 0 && tl < 64) inb[tl] = agg[(size_t)b * C_ + tl];

    float acc = 0.f;
    int   nv  = 0;
    if (tl < FEAT_) {
        const int* gid = gap_ids + (size_t)b * G_;
#pragma unroll 4
        for (int g = 50 * grp; g < 50 * grp + 50; ++g) {
            const int id = gid[g];
            if (id > 0) { ++nv; acc += node_table[(size_t)id * FEAT_ + tl]; }
        }
        if (grp == 1) {
            part[tl] = acc;
            if (tl == 0) nv2 = nv;
        }
    }
    __syncthreads();

    if (grp == 0 && tl < FEAT_) {
        const int nvt = nv + nv2;
        const int nvs = (nvt > 0) ? nvt : 1;
        const float scale = 1.0f / (float)(G_ * nvs);
        const int nid = node_ids[b];
        inb[64 + tl] = (acc + part[tl]) * scale + node_table[(size_t)nid * FEAT_ + tl];
    }
    __syncthreads();

    float o = 0.f;
    if (tl < FEAT_) {
        o = (grp == 0) ? out_b[tl] : 0.f;
        const int i0 = (grp == 0) ? 0 : 118;
        const int i1 = (grp == 0) ? 118 : CAT_;
#pragma unroll 4
        for (int i = i0; i < i1; ++i) o += inb[i] * out_W[i * FEAT_ + tl];
        if (grp == 1) part[tl] = o;
    }
    __syncthreads();

    if (grp == 0 && tl < FEAT_)
        out[(size_t)b * FEAT_ + tl] = o + part[tl];
}

// ---------------------------------------------------------------------------
extern "C" void kernel_launch(void* const* d_in, const int* in_sizes, int n_in,
                              void* d_out, int out_size, void* d_ws, size_t ws_size,
                              hipStream_t stream) {
    const float* node_table = (const float*)d_in[0];
    const float* edge_table = (const float*)d_in[1];
    const float* time_w     = (const float*)d_in[2];
    const float* proj_W     = (const float*)d_in[3];
    const float* proj_b     = (const float*)d_in[4];
    const float* tok_ln_s   = (const float*)d_in[5];
    const float* tok_ln_b   = (const float*)d_in[6];
    const float* tok_W1     = (const float*)d_in[7];
    const float* tok_b1     = (const float*)d_in[8];
    const float* tok_W2     = (const float*)d_in[9];
    const float* tok_b2     = (const float*)d_in[10];
    const float* ch_ln_s    = (const float*)d_in[11];
    const float* ch_ln_b    = (const float*)d_in[12];
    const float* ch_W1      = (const float*)d_in[13];
    const float* ch_b1      = (const float*)d_in[14];
    const float* ch_W2      = (const float*)d_in[15];
    const float* ch_b2      = (const float*)d_in[16];
    const float* out_W      = (const float*)d_in[17];
    const float* out_b      = (const float*)d_in[18];
    const int*   node_ids   = (const int*)d_in[19];
    const int*   nbr_nids   = (const int*)d_in[20];
    const int*   nbr_eids   = (const int*)d_in[21];
    const int*   gap_ids    = (const int*)d_in[22];
    const float* node_times = (const float*)d_in[23];
    const float* nbr_times  = (const float*)d_in[24];

    float* agg_buf = (float*)d_ws;                       // B*C f32 = 2 MiB
    _Float16* pw   = (_Float16*)(agg_buf + (size_t)B_ * C_);
    _Float16* pW   = pw;               // 64*288   = 18432
    _Float16* pT1  = pW  + 18432;      // 2*32*64  = 4096
    _Float16* pT2  = pT1 + 4096;       // 2*64*32  = 4096
    _Float16* pC1  = pT2 + 4096;       // 2*256*64 = 32768
    _Float16* pC2  = pC1 + 32768;      // 2*64*256 = 32768
    float* outp    = (float*)d_out;

    prepack_kernel<<<64, 256, 0, stream>>>(proj_W, tok_W1, tok_W2, ch_W1, ch_W2,
                                           pW, pT1, pT2, pC1, pC2);
    fused_kernel<<<B_ / 2, 256, 0, stream>>>(edge_table, time_w, pW, proj_b,
                                             nbr_nids, nbr_eids, node_times, nbr_times,
                                             tok_ln_s, tok_ln_b, tok_b1, tok_b2,
                                             ch_ln_s, ch_ln_b, ch_b1, ch_b2,
                                             pT1, pT2, pC1, pC2,
                                             agg_buf);
    out_kernel<<<B_, 384, 0, stream>>>(node_table, agg_buf, out_W, out_b,
                                       node_ids, gap_ids, outp);
}

// Round 8
// 540.689 us; speedup vs baseline: 1.7805x; 1.4356x over previous
//
#include <hip/hip_runtime.h>
#include <math.h>

#define B_    8192
#define K_    64
#define C_    64
#define FEAT_ 172
#define TDIM_ 100
#define TOKH_ 32
#define CHH_  256
#define G_    100
#define L_    2
#define CAT_  236      // C_+FEAT_

typedef _Float16 f16x8 __attribute__((ext_vector_type(8)));
typedef _Float16 f16x4 __attribute__((ext_vector_type(4)));
typedef float    f32x4 __attribute__((ext_vector_type(4)));

// Fast exact-range cos: f32 product (same rounding as the jax ref), f64 range
// reduction (exact for |p|<=2e6), hardware v_cos (takes revolutions).
__device__ __forceinline__ float fast_cos(float p) {
    const double rev = (double)p * 0.15915494309189535;   // p / 2pi
    const double fr  = rev - __builtin_rint(rev);         // [-0.5, 0.5]
#if __has_builtin(__builtin_amdgcn_cosf)
    return __builtin_amdgcn_cosf((float)fr);
#else
    return __cosf(6.283185307179586f * (float)fr);
#endif
}

// GELU via A&S 7.1.25 erf (|err|<2.5e-5), v_rcp instead of fdiv: ~13 VALU.
__device__ __forceinline__ float gelu_f(float x) {
    const float z  = x * 0.70710678118654752f;
    const float az = fabsf(z);
    const float t  = __builtin_amdgcn_rcpf(fmaf(0.47047f, az, 1.0f));
    const float poly = t * (0.3480242f + t * (-0.0958798f + t * 0.7478556f));
    const float e  = __expf(-az * az);
    float erfv = fmaf(-poly, e, 1.0f);
    erfv = copysignf(erfv, z);
    return 0.5f * x * (1.0f + erfv);
}

// ---------------------------------------------------------------------------
// Prepack weights to f16. pW layout (64 x 288): cols 0..171 = edge weights,
// 172..175 = 0, 176..275 = time weights (d = col-176), 276..287 = 0.
// pOW layout (176 x 256): pOW[n][k] = out_W[k][n], zero-padded (n>=172, k>=236).
// ---------------------------------------------------------------------------
__global__ __launch_bounds__(256)
void prepack_kernel(const float* __restrict__ proj_W,
                    const float* __restrict__ tW1, const float* __restrict__ tW2,
                    const float* __restrict__ cW1, const float* __restrict__ cW2,
                    const float* __restrict__ out_W,
                    _Float16* __restrict__ pW,
                    _Float16* __restrict__ pT1, _Float16* __restrict__ pT2,
                    _Float16* __restrict__ pC1, _Float16* __restrict__ pC2,
                    _Float16* __restrict__ pOW) {
    const int stride = gridDim.x * blockDim.x;
    const int t0 = blockIdx.x * blockDim.x + threadIdx.x;
    for (int i = t0; i < 64 * 288; i += stride) {
        const int c = i / 288, ii = i % 288;
        float v = 0.f;
        if (ii < 172) v = proj_W[ii * 64 + c];
        else if (ii >= 176 && ii < 276) v = proj_W[(ii - 4) * 64 + c];
        pW[i] = (_Float16)v;
    }
    // pT1[l][j][k] = tW1[l][k][j]   tW1: (2,64,32)
    for (int i = t0; i < 2 * 32 * 64; i += stride) {
        const int l = i / 2048, rem = i % 2048, j = rem / 64, k = rem % 64;
        pT1[i] = (_Float16)tW1[l * 2048 + k * 32 + j];
    }
    // pT2[l][k][j] = tW2[l][j][k]   tW2: (2,32,64)
    for (int i = t0; i < 2 * 64 * 32; i += stride) {
        const int l = i / 2048, rem = i % 2048, k = rem / 32, j = rem % 32;
        pT2[i] = (_Float16)tW2[l * 2048 + j * 64 + k];
    }
    // pC1[l][n][c] = cW1[l][c][n]   cW1: (2,64,256)
    for (int i = t0; i < 2 * 256 * 64; i += stride) {
        const int l = i / 16384, rem = i % 16384, n = rem / 64, c = rem % 64;
        pC1[i] = (_Float16)cW1[l * 16384 + c * 256 + n];
    }
    // pC2[l][c][n] = cW2[l][n][c]   cW2: (2,256,64)
    for (int i = t0; i < 2 * 64 * 256; i += stride) {
        const int l = i / 16384, rem = i % 16384, c = rem / 256, n = rem % 256;
        pC2[i] = (_Float16)cW2[l * 16384 + n * 64 + c];
    }
    // pOW[n][k] = out_W[k][n]  (176 x 256, zero-padded)
    for (int i = t0; i < 176 * 256; i += stride) {
        const int n = i / 256, k = i % 256;
        pOW[i] = (n < FEAT_ && k < CAT_) ? (_Float16)out_W[k * FEAT_ + n]
                                         : (_Float16)0.f;
    }
}

// ---------------------------------------------------------------------------
// Fused kernel, TWO batch elements per block. Weight frags loaded once per
// wave feed 2 MFMAs; dual independent chains hide latency. LDS 53.2 KB ->
// 3 blocks/CU (LDS-bound), so __launch_bounds__(256,3): VGPR cap ~170 gives
// the scheduler room to prefetch weight frags (r7 capped at 128, used 108).
// Channel q-loop fully unrolled for cross-iteration load hoisting.
// ---------------------------------------------------------------------------
__global__ __launch_bounds__(256, 3)
void fused_kernel(const float* __restrict__ edge_table,
                  const float* __restrict__ time_w,
                  const _Float16* __restrict__ pW,
                  const float* __restrict__ proj_b,
                  const int*   __restrict__ nbr_nids,
                  const int*   __restrict__ nbr_eids,
                  const float* __restrict__ node_times,
                  const float* __restrict__ nbr_times,
                  const float* __restrict__ tok_ln_s, const float* __restrict__ tok_ln_b,
                  const float* __restrict__ tok_b1,   const float* __restrict__ tok_b2,
                  const float* __restrict__ ch_ln_s,  const float* __restrict__ ch_ln_b,
                  const float* __restrict__ ch_b1,    const float* __restrict__ ch_b2,
                  const _Float16* __restrict__ pT1, const _Float16* __restrict__ pT2,
                  const _Float16* __restrict__ pC1, const _Float16* __restrict__ pC2,
                  float* __restrict__ agg_out) {
    __shared__ __attribute__((aligned(16))) float    xf[2][64 * 68];   // 34816 B
    __shared__ __attribute__((aligned(16))) _Float16 sh[2][64 * 72];   // 18432 B

    const int bid  = blockIdx.x;
    const int t    = threadIdx.x;
    const int lane = t & 63;
    const int w    = t >> 6;
    const int r    = lane & 15;
    const int g    = lane >> 4;
    const int row16 = 16 * w + r;

    // ================= proj phase (both b, shared pW frags) =================
    {
        const float* erow[2];
        bool  nz[2];
        float dt[2];
#pragma unroll
        for (int bb = 0; bb < 2; ++bb) {
            const size_t bgl = (size_t)(2 * bid + bb) * K_ + row16;
            erow[bb] = edge_table + (size_t)nbr_eids[bgl] * FEAT_;
            nz[bb]   = (nbr_nids[bgl] == 0);
            dt[bb]   = node_times[2 * bid + bb] - nbr_times[bgl];
        }

        f32x4 pacc[2][4];
#pragma unroll
        for (int nt = 0; nt < 4; ++nt) {
            const f32x4 pb = *(const f32x4*)&proj_b[16 * nt + 4 * g];
            pacc[0][nt] = pb; pacc[1][nt] = pb;
        }

        const int c0b = 8 * g;
#pragma unroll
        for (int kk = 0; kk < 9; ++kk) {
            const int c0 = 32 * kk + c0b;
            f16x8 af[4];
#pragma unroll
            for (int nt = 0; nt < 4; ++nt)
                af[nt] = *(const f16x8*)&pW[(16 * nt + r) * 288 + c0];
            f16x8 bf[2];
#pragma unroll
            for (int bb = 0; bb < 2; ++bb) {
                if (c0 + 8 <= FEAT_) {
                    const float4 v0 = *(const float4*)(erow[bb] + c0);
                    const float4 v1 = *(const float4*)(erow[bb] + c0 + 4);
                    bf[bb][0]=(_Float16)v0.x; bf[bb][1]=(_Float16)v0.y;
                    bf[bb][2]=(_Float16)v0.z; bf[bb][3]=(_Float16)v0.w;
                    bf[bb][4]=(_Float16)v1.x; bf[bb][5]=(_Float16)v1.y;
                    bf[bb][6]=(_Float16)v1.z; bf[bb][7]=(_Float16)v1.w;
                } else if (c0 < 176) {       // c0==168: edge 168..171 + pad
                    const float4 v0 = *(const float4*)(erow[bb] + 168);
                    bf[bb][0]=(_Float16)v0.x; bf[bb][1]=(_Float16)v0.y;
                    bf[bb][2]=(_Float16)v0.z; bf[bb][3]=(_Float16)v0.w;
                    bf[bb][4]=(_Float16)0.f; bf[bb][5]=(_Float16)0.f;
                    bf[bb][6]=(_Float16)0.f; bf[bb][7]=(_Float16)0.f;
                } else {                     // time cols
                    const int d0 = c0 - 176;
#pragma unroll
                    for (int i = 0; i < 8; ++i) {
                        const int d = d0 + i;
                        float tv = 0.f;
                        if (d < TDIM_) tv = fast_cos(dt[bb] * time_w[d]);
                        bf[bb][i] = nz[bb] ? (_Float16)0.f : (_Float16)tv;
                    }
                }
            }
#pragma unroll
            for (int nt = 0; nt < 4; ++nt) {
                pacc[0][nt] = __builtin_amdgcn_mfma_f32_16x16x32_f16(af[nt], bf[0], pacc[0][nt], 0, 0, 0);
                pacc[1][nt] = __builtin_amdgcn_mfma_f32_16x16x32_f16(af[nt], bf[1], pacc[1][nt], 0, 0, 0);
            }
        }
#pragma unroll
        for (int bb = 0; bb < 2; ++bb)
#pragma unroll
            for (int nt = 0; nt < 4; ++nt)
                *(f32x4*)&xf[bb][row16 * 68 + 16 * nt + 4 * g] = pacc[bb][nt];
    }
    __syncthreads();

    // ================= mixer layers =================
    for (int l = 0; l < L_; ++l) {
        // ---- token LN (over k, per c), both b ----
#pragma unroll
        for (int bb = 0; bb < 2; ++bb) {
            const int c0 = row16;
            float xv[16], s = 0.f, ss = 0.f;
#pragma unroll
            for (int u = 0; u < 16; ++u) {
                const float v = xf[bb][(16 * g + u) * 68 + c0];
                xv[u] = v; s += v; ss += v * v;
            }
            s += __shfl_xor(s, 16); ss += __shfl_xor(ss, 16);
            s += __shfl_xor(s, 32); ss += __shfl_xor(ss, 32);
            const float mean = s * 0.015625f;
            const float rstd = rsqrtf(ss * 0.015625f - mean * mean + 1e-5f);
            const float* tls = tok_ln_s + l * 64 + 16 * g;
            const float* tlb = tok_ln_b + l * 64 + 16 * g;
            f16x8 h0, h1;
#pragma unroll
            for (int u = 0; u < 8; ++u)
                h0[u] = (_Float16)((xv[u] - mean) * rstd * tls[u] + tlb[u]);
#pragma unroll
            for (int u = 0; u < 8; ++u)
                h1[u] = (_Float16)((xv[8 + u] - mean) * rstd * tls[8 + u] + tlb[8 + u]);
            *(f16x8*)&sh[bb][c0 * 72 + 16 * g]     = h0;   // xh^T[c][k]
            *(f16x8*)&sh[bb][c0 * 72 + 16 * g + 8] = h1;
        }
        // ---- token G1 + G2 + residual (weight frags shared across b) ----
        {
            const _Float16* W1 = pT1 + l * 2048;   // [j][k]
            const _Float16* W2 = pT2 + l * 2048;   // [k][j]
            // read xh frags for both b BEFORE hb overwrites (same rows)
            f16x8 tb0[2], tb1[2];
#pragma unroll
            for (int bb = 0; bb < 2; ++bb) {
                tb0[bb] = *(const f16x8*)&sh[bb][row16 * 72 + 8 * g];
                tb1[bb] = *(const f16x8*)&sh[bb][row16 * 72 + 32 + 8 * g];
            }
#pragma unroll
            for (int nt = 0; nt < 2; ++nt) {
                const f16x8 a0 = *(const f16x8*)&W1[(16 * nt + r) * 64 + 8 * g];
                const f16x8 a1 = *(const f16x8*)&W1[(16 * nt + r) * 64 + 32 + 8 * g];
                const f32x4 bias = *(const f32x4*)&tok_b1[l * 32 + 16 * nt + 4 * g];
#pragma unroll
                for (int bb = 0; bb < 2; ++bb) {
                    f32x4 acc = bias;
                    acc = __builtin_amdgcn_mfma_f32_16x16x32_f16(a0, tb0[bb], acc, 0, 0, 0);
                    acc = __builtin_amdgcn_mfma_f32_16x16x32_f16(a1, tb1[bb], acc, 0, 0, 0);
                    f16x4 hq;
#pragma unroll
                    for (int jj = 0; jj < 4; ++jj) hq[jj] = (_Float16)gelu_f(acc[jj]);
                    *(f16x4*)&sh[bb][row16 * 72 + 16 * nt + 4 * g] = hq;   // hb cols 0..31
                }
            }
            f16x8 a[2];
#pragma unroll
            for (int bb = 0; bb < 2; ++bb)
                a[bb] = *(const f16x8*)&sh[bb][row16 * 72 + 8 * g];   // H: c=row16
#pragma unroll
            for (int nt = 0; nt < 4; ++nt) {
                const int kcol = 16 * nt + r;
                const float bk = tok_b2[l * 64 + kcol];
                const f16x8 bf = *(const f16x8*)&W2[kcol * 32 + 8 * g];
#pragma unroll
                for (int bb = 0; bb < 2; ++bb) {
                    f32x4 acc = {bk, bk, bk, bk};
                    acc = __builtin_amdgcn_mfma_f32_16x16x32_f16(a[bb], bf, acc, 0, 0, 0);
                    float* p = &xf[bb][kcol * 68 + 16 * w + 4 * g];
                    const f32x4 old = *(const f32x4*)p;
                    *(f32x4*)p = old + acc;   // wave's own c-slice only
                }
            }
        }
        __syncthreads();   // token residual visible before channel LN

        // ---- channel LN (over c, per k), both b ----
#pragma unroll
        for (int bb = 0; bb < 2; ++bb) {
            const int k0 = row16;
            f32x4 cv[4];
            float s = 0.f, ss = 0.f;
#pragma unroll
            for (int uu = 0; uu < 4; ++uu) {
                cv[uu] = *(const f32x4*)&xf[bb][k0 * 68 + 16 * g + 4 * uu];
#pragma unroll
                for (int e = 0; e < 4; ++e) { s += cv[uu][e]; ss += cv[uu][e] * cv[uu][e]; }
            }
            s += __shfl_xor(s, 16); ss += __shfl_xor(ss, 16);
            s += __shfl_xor(s, 32); ss += __shfl_xor(ss, 32);
            const float mean = s * 0.015625f;
            const float rstd = rsqrtf(ss * 0.015625f - mean * mean + 1e-5f);
            const float* cls = ch_ln_s + l * 64 + 16 * g;
            const float* clb = ch_ln_b + l * 64 + 16 * g;
            f16x8 h0, h1;
#pragma unroll
            for (int uu = 0; uu < 4; ++uu)
#pragma unroll
                for (int e = 0; e < 4; ++e) {
                    const float hv = (cv[uu][e] - mean) * rstd * cls[4 * uu + e] + clb[4 * uu + e];
                    if (uu < 2) h0[4 * uu + e] = (_Float16)hv;
                    else        h1[4 * (uu - 2) + e] = (_Float16)hv;
                }
            *(f16x8*)&sh[bb][k0 * 72 + 16 * g]     = h0;   // xh[k][c]
            *(f16x8*)&sh[bb][k0 * 72 + 16 * g + 8] = h1;
        }
        // ---- channel MLP (shared Wc1/Wc2 frags; q fully unrolled) ----
        {
            f16x8 ca0[2], ca1[2];
#pragma unroll
            for (int bb = 0; bb < 2; ++bb) {
                ca0[bb] = *(const f16x8*)&sh[bb][row16 * 72 + 8 * g];
                ca1[bb] = *(const f16x8*)&sh[bb][row16 * 72 + 32 + 8 * g];
            }
            const _Float16* Wc1 = pC1 + l * 16384;   // [n][c]
            const _Float16* Wc2 = pC2 + l * 16384;   // [c][n]
            f32x4 cacc[2][4];
#pragma unroll
            for (int nt = 0; nt < 4; ++nt) {
                const f32x4 cb = *(const f32x4*)&ch_b2[l * 64 + 16 * nt + 4 * g];
                cacc[0][nt] = cb; cacc[1][nt] = cb;
            }
#pragma unroll
            for (int q = 0; q < 4; ++q) {
#pragma unroll
                for (int nt = 0; nt < 4; ++nt) {
                    const int nrow = 64 * q + 16 * nt + r;
                    const f16x8 a0 = *(const f16x8*)&Wc1[nrow * 64 + 8 * g];
                    const f16x8 a1 = *(const f16x8*)&Wc1[nrow * 64 + 32 + 8 * g];
                    const f32x4 hb1 = *(const f32x4*)&ch_b1[l * 256 + 64 * q + 16 * nt + 4 * g];
#pragma unroll
                    for (int bb = 0; bb < 2; ++bb) {
                        f32x4 acc = hb1;
                        acc = __builtin_amdgcn_mfma_f32_16x16x32_f16(a0, ca0[bb], acc, 0, 0, 0);
                        acc = __builtin_amdgcn_mfma_f32_16x16x32_f16(a1, ca1[bb], acc, 0, 0, 0);
                        f16x4 hq;
#pragma unroll
                        for (int jj = 0; jj < 4; ++jj) hq[jj] = (_Float16)gelu_f(acc[jj]);
                        *(f16x4*)&sh[bb][row16 * 72 + 16 * nt + 4 * g] = hq;   // H cols 0..63
                    }
                }
#pragma unroll
                for (int ks = 0; ks < 2; ++ks) {
                    f16x8 bh[2];
#pragma unroll
                    for (int bb = 0; bb < 2; ++bb)
                        bh[bb] = *(const f16x8*)&sh[bb][row16 * 72 + 32 * ks + 8 * g];
#pragma unroll
                    for (int nt2 = 0; nt2 < 4; ++nt2) {
                        const f16x8 a2 = *(const f16x8*)&Wc2[(16 * nt2 + r) * 256 + 64 * q + 32 * ks + 8 * g];
                        cacc[0][nt2] = __builtin_amdgcn_mfma_f32_16x16x32_f16(a2, bh[0], cacc[0][nt2], 0, 0, 0);
                        cacc[1][nt2] = __builtin_amdgcn_mfma_f32_16x16x32_f16(a2, bh[1], cacc[1][nt2], 0, 0, 0);
                    }
                }
            }
#pragma unroll
            for (int bb = 0; bb < 2; ++bb)
#pragma unroll
                for (int nt2 = 0; nt2 < 4; ++nt2) {
                    float* p = &xf[bb][row16 * 68 + 16 * nt2 + 4 * g];
                    const f32x4 old = *(const f32x4*)p;
                    *(f32x4*)p = old + cacc[bb][nt2];
                }
        }
        __syncthreads();   // layer complete
    }

    // ---- agg: mean over k per c, both b ----
#pragma unroll
    for (int bb = 0; bb < 2; ++bb) {
        float ssum = 0.f;
#pragma unroll
        for (int u = 0; u < 16; ++u) ssum += xf[bb][(16 * g + u) * 68 + row16];
        ssum += __shfl_xor(ssum, 16);
        ssum += __shfl_xor(ssum, 32);
        if (g == 0) agg_out[(size_t)(2 * bid + bb) * 64 + row16] = ssum * 0.015625f;
    }
}

// ---------------------------------------------------------------------------
// Kernel 3: 16 batch rows per block. Phase 1: 16 thread-groups gather the
// gap rows (broadcast ids, coalesced 64B col-strips) and build
// inb16[16][264] f16 in LDS (cols 0..63 agg, 64..235 agg_node+node_feat,
// 236.. zero). Phase 2: GEMM 16x172x236 via swapped-operand MFMA; A-frags
// stream from prepacked pOW[176][256], D col = b-row -> f32x4 stores.
// ---------------------------------------------------------------------------
__global__ __launch_bounds__(256)
void out_kernel(const float* __restrict__ node_table,
                const float* __restrict__ agg,
                const _Float16* __restrict__ pOW,
                const float* __restrict__ out_b,
                const int*   __restrict__ node_ids,
                const int*   __restrict__ gap_ids,
                float* __restrict__ out) {
    __shared__ __attribute__((aligned(16))) _Float16 inb16[16][264];
    const int t     = threadIdx.x;
    const int bbase = blockIdx.x * 16;
    const int m     = t >> 4;      // local b row 0..15
    const int c16   = t & 15;
    const int b     = bbase + m;

    // agg cols 0..63
#pragma unroll
    for (int j = 0; j < 4; ++j)
        inb16[m][c16 + 16 * j] = (_Float16)agg[(size_t)b * C_ + c16 + 16 * j];
    // zero pad cols 236..263
    {
        const int c0 = 236 + c16;
        if (c0 < 264) inb16[m][c0] = (_Float16)0.f;
        const int c1 = 252 + c16;
        if (c1 < 264) inb16[m][c1] = (_Float16)0.f;
    }
    // gap gather: group of 16 threads shares ids (broadcast), strided cols
    {
        const int* gid = gap_ids + (size_t)b * G_;
        float acc[11];
#pragma unroll
        for (int j = 0; j < 11; ++j) acc[j] = 0.f;
        int nv = 0;
        for (int g = 0; g < G_; ++g) {
            const int id = gid[g];
            if (id > 0) {
                ++nv;
                const float* row = node_table + (size_t)id * FEAT_;
#pragma unroll
                for (int j = 0; j < 11; ++j) {
                    const int c = c16 + 16 * j;
                    if (c < FEAT_) acc[j] += row[c];
                }
            }
        }
        const float scale = 1.0f / (float)(G_ * (nv > 0 ? nv : 1));
        const float* nrow = node_table + (size_t)node_ids[b] * FEAT_;
#pragma unroll
        for (int j = 0; j < 11; ++j) {
            const int c = c16 + 16 * j;
            if (c < FEAT_)
                inb16[m][64 + c] = (_Float16)(fmaf(acc[j], scale, nrow[c]));
        }
    }
    __syncthreads();

    // MFMA GEMM: 11 n-tiles over 4 waves
    const int lane = t & 63;
    const int w = t >> 6;
    const int r = lane & 15;
    const int g = lane >> 4;
    f16x8 bf[8];
#pragma unroll
    for (int kk = 0; kk < 8; ++kk)
        bf[kk] = *(const f16x8*)&inb16[r][32 * kk + 8 * g];
    for (int nt = w; nt < 11; nt += 4) {
        const int n0 = nt * 16 + 4 * g;
        const int bidx = (n0 + 4 <= FEAT_) ? n0 : (FEAT_ - 4);  // clamp (masked lanes)
        f32x4 acc = *(const f32x4*)&out_b[bidx];
#pragma unroll
        for (int kk = 0; kk < 8; ++kk) {
            const f16x8 af = *(const f16x8*)&pOW[(nt * 16 + r) * 256 + 32 * kk + 8 * g];
            acc = __builtin_amdgcn_mfma_f32_16x16x32_f16(af, bf[kk], acc, 0, 0, 0);
        }
        // D: col = r -> b-row bbase+r; rows n0..n0+3 contiguous -> f32x4 store
        if (n0 + 4 <= FEAT_)
            *(f32x4*)&out[(size_t)(bbase + r) * FEAT_ + n0] = acc;
    }
}

// ---------------------------------------------------------------------------
extern "C" void kernel_launch(void* const* d_in, const int* in_sizes, int n_in,
                              void* d_out, int out_size, void* d_ws, size_t ws_size,
                              hipStream_t stream) {
    const float* node_table = (const float*)d_in[0];
    const float* edge_table = (const float*)d_in[1];
    const float* time_w     = (const float*)d_in[2];
    const float* proj_W     = (const float*)d_in[3];
    const float* proj_b     = (const float*)d_in[4];
    const float* tok_ln_s   = (const float*)d_in[5];
    const float* tok_ln_b   = (const float*)d_in[6];
    const float* tok_W1     = (const float*)d_in[7];
    const float* tok_b1     = (const float*)d_in[8];
    const float* tok_W2     = (const float*)d_in[9];
    const float* tok_b2     = (const float*)d_in[10];
    const float* ch_ln_s    = (const float*)d_in[11];
    const float* ch_ln_b    = (const float*)d_in[12];
    const float* ch_W1      = (const float*)d_in[13];
    const float* ch_b1      = (const float*)d_in[14];
    const float* ch_W2      = (const float*)d_in[15];
    const float* ch_b2      = (const float*)d_in[16];
    const float* out_W      = (const float*)d_in[17];
    const float* out_b      = (const float*)d_in[18];
    const int*   node_ids   = (const int*)d_in[19];
    const int*   nbr_nids   = (const int*)d_in[20];
    const int*   nbr_eids   = (const int*)d_in[21];
    const int*   gap_ids    = (const int*)d_in[22];
    const float* node_times = (const float*)d_in[23];
    const float* nbr_times  = (const float*)d_in[24];

    float* agg_buf = (float*)d_ws;                       // B*C f32 = 2 MiB
    _Float16* pw   = (_Float16*)(agg_buf + (size_t)B_ * C_);
    _Float16* pW   = pw;               // 64*288   = 18432
    _Float16* pT1  = pW  + 18432;      // 2*32*64  = 4096
    _Float16* pT2  = pT1 + 4096;       // 2*64*32  = 4096
    _Float16* pC1  = pT2 + 4096;       // 2*256*64 = 32768
    _Float16* pC2  = pC1 + 32768;      // 2*64*256 = 32768
    _Float16* pOW  = pC2 + 32768;      // 176*256  = 45056
    float* outp    = (float*)d_out;

    prepack_kernel<<<64, 256, 0, stream>>>(proj_W, tok_W1, tok_W2, ch_W1, ch_W2,
                                           out_W, pW, pT1, pT2, pC1, pC2, pOW);
    fused_kernel<<<B_ / 2, 256, 0, stream>>>(edge_table, time_w, pW, proj_b,
                                             nbr_nids, nbr_eids, node_times, nbr_times,
                                             tok_ln_s, tok_ln_b, tok_b1, tok_b2,
                                             ch_ln_s, ch_ln_b, ch_b1, ch_b2,
                                             pT1, pT2, pC1, pC2,
                                             agg_buf);
    out_kernel<<<B_ / 16, 256, 0, stream>>>(node_table, agg_buf, pOW, out_b,
                                            node_ids, gap_ids, outp);
}